// Round 2
// baseline (6178.003 us; speedup 1.0000x reference)
//
#include <hip/hip_runtime.h>

// ---------------------------------------------------------------------------
// TwoHeadLSTM on MI355X.
// Persistent cooperative kernel, 256 WGs x 256 thr (1 WG/CU).
//  - WG g owns hidden indices j in [4g,4g+4) for BOTH layers, i.e. 16 packed
//    rows (4 gates x 4 j) of each of {W_hh0, W_ih1, W_hh1}. Those rows are
//    read from the ORIGINAL fp32 tensors and converted to f16 directly into
//    LDS at kernel start (no big global staging buffer -> tiny workspace).
//  - Embedding-side layer0 GEMM precomputed as ihb[256][26][16] (idx 25=pad).
//  - Per phase p: layer0 step t=p and layer1 step t=p-1 run concurrently
//    (both read the same h1 buffer); ONE grid barrier per phase.
//  - h state published as f16 [2][64][1024], double-buffered by parity.
//  - Custom 2-level barrier, phase-indexed counters (zeroed by memset each
//    launch) + __threadfence() release/acquire (cross-XCD L2 wb/inv).
// ---------------------------------------------------------------------------

typedef _Float16 h16;
typedef h16  h16x8 __attribute__((ext_vector_type(8)));
typedef float f32x4 __attribute__((ext_vector_type(4)));

#define NWG 256
#define WGT 256

// workspace layout (bytes) — total 1,229,824 B (~1.2 MB)
#define OFF_IHB   ((size_t)0)         // [256][26][16] f32 = 425984
#define OFF_B1    ((size_t)425984)    // [256][16] f32     = 16384
#define OFF_H1    ((size_t)442368)    // [2][64][1024] f16 = 262144
#define OFF_H2    ((size_t)704512)    // [2][64][1024] f16 = 262144
#define OFF_SYNC  ((size_t)966656)    // [256][64][4] u32  = 262144 (16B slots)
#define ZERO_OFF  OFF_H1
#define ZERO_BYTES ((size_t)(262144 + 262144 + 262144))

#define LDS_W     99072               // 3*16*1032 f16 (rows padded +8)
#define LDS_TOTAL (LDS_W + 10240)     // + 4 waves * 2 tiles * 16*20 f32

__device__ __forceinline__ float sigm(float x) {
  return 1.0f / (1.0f + __expf(-x));
}
__device__ __forceinline__ float tanh_(float x) {
  float e = __expf(2.0f * x);        // inf-safe: 1 - 2/(e+1)
  return 1.0f - 2.0f / (e + 1.0f);
}

// ------------------------- prep kernels ------------------------------------

// ihb[g][e][c] = (emb[e] . W_ih0[row(c,g)]) + b_ih0[row] + b_hh0[row]
// row(c,g) = (gate<<10) + (g<<2) + jj  with gate=c&3, jj=c>>2 (c = jj*4+gate)
__global__ void __launch_bounds__(64) prep_ihb(
    const float* __restrict__ emb, const float* __restrict__ wih0,
    const float* __restrict__ bih0, const float* __restrict__ bhh0,
    float* __restrict__ ihb) {
  int g = blockIdx.x / 26, e = blockIdx.x % 26;
  int l = threadIdx.x, c = l & 15, q = l >> 4;
  int gate = c & 3, jj = c >> 2;
  int row = (gate << 10) + (g << 2) + jj;
  float s = 0.f;
  if (e < 25) {
    const float* er = emb + e * 128 + q * 32;
    const float* wr = wih0 + row * 128 + q * 32;
#pragma unroll
    for (int k = 0; k < 32; k += 4) {
      float4 a = *(const float4*)(er + k);
      float4 b = *(const float4*)(wr + k);
      s += a.x * b.x + a.y * b.y + a.z * b.z + a.w * b.w;
    }
  }
  s += __shfl_xor(s, 16);
  s += __shfl_xor(s, 32);
  if (q == 0) ihb[(g * 26 + e) * 16 + c] = s + bih0[row] + bhh0[row];
}

__global__ void __launch_bounds__(256) prep_bias(
    const float* __restrict__ bih1, const float* __restrict__ bhh1,
    float* __restrict__ bias1) {
  int i = blockIdx.x * 256 + threadIdx.x;
  if (i < 4096) {
    int g = i >> 4, c = i & 15, gate = c & 3, jj = c >> 2;
    int row = (gate << 10) + (g << 2) + jj;
    bias1[i] = bih1[row] + bhh1[row];
  }
}

// ------------------------- grid barrier ------------------------------------
// Per phase: 64 slots of 4 u32 (16B). Slots 0..7 group counters (32 WGs each),
// slot 8 super-counter, slot 15 release flag.
__device__ __forceinline__ void gbar(unsigned* syncb, int p) {
  __syncthreads();                    // per-wave vmcnt(0) drain before barrier
  if (threadIdx.x == 0) {
    __threadfence();                  // release: L2 writeback (agent scope)
    unsigned* base = syncb + (size_t)p * 256;
    const int grp = (int)(blockIdx.x >> 5);
    if (__hip_atomic_fetch_add(base + grp * 4, 1u, __ATOMIC_RELAXED,
                               __HIP_MEMORY_SCOPE_AGENT) == 31u) {
      if (__hip_atomic_fetch_add(base + 8 * 4, 1u, __ATOMIC_RELAXED,
                                 __HIP_MEMORY_SCOPE_AGENT) == 7u) {
        __hip_atomic_store(base + 15 * 4, 1u, __ATOMIC_RELEASE,
                           __HIP_MEMORY_SCOPE_AGENT);
      }
    }
    while (__hip_atomic_load(base + 15 * 4, __ATOMIC_RELAXED,
                             __HIP_MEMORY_SCOPE_AGENT) == 0u) {
      __builtin_amdgcn_s_sleep(2);
    }
    __threadfence();                  // acquire: L1/L2 invalidate
  }
  __syncthreads();
}

// ------------------------- main persistent kernel --------------------------

__global__ void __launch_bounds__(WGT, 1) lstm_main(
    const float* __restrict__ whh0, const float* __restrict__ wih1,
    const float* __restrict__ whh1, const float* __restrict__ ihb,
    const float* __restrict__ bias1, h16* __restrict__ h1buf,
    h16* __restrict__ h2buf, unsigned* __restrict__ syncb,
    const int* __restrict__ tokL, const int* __restrict__ tokR,
    const int* __restrict__ lenL, const int* __restrict__ lenR) {
  extern __shared__ char lds[];
  h16* wlds = (h16*)lds;                      // [3][16][1032] f16
  float* scrb = (float*)(lds + LDS_W);        // [4 waves][2][16][20] f32
  const int g = (int)blockIdx.x;
  const int tid = (int)threadIdx.x;
  const int w = tid >> 6, lane = tid & 63;

  // ---- stage this WG's 48 weight rows: global fp32 -> LDS f16 (once) ----
  // 6144 chunks of 8 floats: i -> m(matrix), c(packed col), kc(k-chunk)
  for (int i = tid; i < 6144; i += WGT) {
    int m = i >> 11, rem = i & 2047, c = rem >> 7, kc = rem & 127;
    int row = ((c & 3) << 10) + (g << 2) + (c >> 2);
    const float* src =
        (m == 0 ? whh0 : (m == 1 ? wih1 : whh1)) + row * 1024 + kc * 8;
    float4 v0 = *(const float4*)(src);
    float4 v1 = *(const float4*)(src + 4);
    h16x8 o;
    o[0] = (h16)v0.x; o[1] = (h16)v0.y; o[2] = (h16)v0.z; o[3] = (h16)v0.w;
    o[4] = (h16)v1.x; o[5] = (h16)v1.y; o[6] = (h16)v1.z; o[7] = (h16)v1.w;
    *(h16x8*)(wlds + (m * 16 + c) * 1032 + kc * 8) = o;
  }
  __syncthreads();

  const int bl = lane & 15;
  const int brow = 16 * w + bl;               // batch row for A-fragment
  const int koff = (lane >> 4) << 3;          // k sub-offset for MFMA frags
  const int jj = lane >> 4;                   // hidden sub-index for this thread
  const int jglob = (g << 2) + jj;
  const int len_b = (brow < 32) ? lenL[brow] : lenR[brow - 32];
  const int tokoff = (brow < 32) ? brow : (brow - 32);
  const int* tokbase = (brow < 32) ? tokL : tokR;

  const h16* w0p = wlds + (0 * 16 + bl) * 1032 + koff;
  const h16* w1p = wlds + (1 * 16 + bl) * 1032 + koff;
  const h16* w2p = wlds + (2 * 16 + bl) * 1032 + koff;
  float* scr0 = scrb + (w * 2 + 0) * 320;     // 16 rows x 20 f32 (padded)
  float* scr1 = scrb + (w * 2 + 1) * 320;
  const float* ihbg = ihb + (size_t)g * 26 * 16;
  const f32x4 bb = *(const f32x4*)(bias1 + (g << 4) + (jj << 2));

  float c1 = 0.f, h1v = 0.f, c2 = 0.f, h2v = 0.f;

  for (int p = 0; p <= 256; ++p) {
    const int r = p & 1;
    const h16* a1p = h1buf + r * 65536 + brow * 1024 + koff;
    const h16* a2p = h2buf + (r ^ 1) * 65536 + brow * 1024 + koff;

    // token + ihb row (prefetched early, hidden behind MFMA loop)
    int tok = 0;
    if (p < 256) tok = tokbase[p * 32 + tokoff];
    int e = (tok < 0) ? 25 : tok;
    f32x4 ib = *(const f32x4*)(ihbg + (e << 4) + (jj << 2));

    f32x4 acc0 = {0.f, 0.f, 0.f, 0.f};
    f32x4 acc1a = {0.f, 0.f, 0.f, 0.f};
    f32x4 acc1b = {0.f, 0.f, 0.f, 0.f};
#pragma unroll 4
    for (int kk = 0; kk < 32; ++kk) {
      h16x8 a1 = *(const h16x8*)(a1p + (kk << 5));
      h16x8 a2 = *(const h16x8*)(a2p + (kk << 5));
      h16x8 b0 = *(const h16x8*)(w0p + (kk << 5));
      h16x8 b1 = *(const h16x8*)(w1p + (kk << 5));
      h16x8 b2 = *(const h16x8*)(w2p + (kk << 5));
      acc0  = __builtin_amdgcn_mfma_f32_16x16x32_f16(a1, b0, acc0, 0, 0, 0);
      acc1a = __builtin_amdgcn_mfma_f32_16x16x32_f16(a1, b1, acc1a, 0, 0, 0);
      acc1b = __builtin_amdgcn_mfma_f32_16x16x32_f16(a2, b2, acc1b, 0, 0, 0);
    }

    // ---- cell 0: layer0, step t=p ----
    if (p < 256) {
#pragma unroll
      for (int q = 0; q < 4; ++q)
        scr0[((jj << 2) + q) * 20 + bl] = acc0[q];  // D: row=(l>>4)*4+q, col=l&15
      asm volatile("s_waitcnt lgkmcnt(0)" ::: "memory");
      __builtin_amdgcn_sched_barrier(0);
      f32x4 gv = *(const f32x4*)(scr0 + bl * 20 + (jj << 2));
      float gi = gv[0] + ib[0], gf = gv[1] + ib[1];
      float gg = gv[2] + ib[2], go = gv[3] + ib[3];
      if (p < len_b) {
        float iv = sigm(gi), fv = sigm(gf), gt = tanh_(gg), ov = sigm(go);
        c1 = fv * c1 + iv * gt;
        h1v = ov * tanh_(c1);
      }
      h1buf[(r ^ 1) * 65536 + brow * 1024 + jglob] = (h16)h1v;
    }

    // ---- cell 1: layer1, step t=p-1 ----
    if (p >= 1) {
      f32x4 s1 = acc1a + acc1b;
#pragma unroll
      for (int q = 0; q < 4; ++q)
        scr1[((jj << 2) + q) * 20 + bl] = s1[q];
      asm volatile("s_waitcnt lgkmcnt(0)" ::: "memory");
      __builtin_amdgcn_sched_barrier(0);
      f32x4 gv = *(const f32x4*)(scr1 + bl * 20 + (jj << 2));
      float gi = gv[0] + bb[0], gf = gv[1] + bb[1];
      float gg = gv[2] + bb[2], go = gv[3] + bb[3];
      if (p - 1 < len_b) {
        float iv = sigm(gi), fv = sigm(gf), gt = tanh_(gg), ov = sigm(go);
        c2 = fv * c2 + iv * gt;
        h2v = ov * tanh_(c2);
      }
      h2buf[r * 65536 + brow * 1024 + jglob] = (h16)h2v;
    }

    if (p < 256) gbar(syncb, p);
  }
  // final h2 (t=255) lives in h2buf slot 0 (phase 256 writes r=0)
}

// ------------------------- head (lin+relu+out) -----------------------------

__global__ void __launch_bounds__(256) head_kernel(
    const h16* __restrict__ h2, const float* __restrict__ linW,
    const float* __restrict__ linb, const float* __restrict__ outW,
    const float* __restrict__ outb, float* __restrict__ out) {
  __shared__ h16 hl[2048];
  __shared__ float red[4];
  const int b = (int)blockIdx.x >> 2, lq = (int)blockIdx.x & 3;
  const int tid = (int)threadIdx.x;
  {
    int k0 = tid * 8;
    const h16* src = (k0 < 1024) ? (h2 + b * 1024 + k0)
                                 : (h2 + (b + 32) * 1024 + (k0 - 1024));
    *(h16x8*)(hl + k0) = *(const h16x8*)src;
  }
  __syncthreads();
  const int l = lq * 256 + tid;
  float acc = linb[l];
  const float* wr = linW + (size_t)l * 2048;
  for (int k = 0; k < 2048; k += 4) {
    float4 wv = *(const float4*)(wr + k);
    acc += wv.x * (float)hl[k] + wv.y * (float)hl[k + 1] +
           wv.z * (float)hl[k + 2] + wv.w * (float)hl[k + 3];
  }
  float v = fmaxf(acc, 0.f) * outW[l];
  for (int off = 32; off > 0; off >>= 1) v += __shfl_down(v, off);
  if ((tid & 63) == 0) red[tid >> 6] = v;
  __syncthreads();
  if (tid == 0) {
    float s = red[0] + red[1] + red[2] + red[3];
    if (lq == 0) s += outb[0];
    atomicAdd(out + b, s);
  }
}

// ------------------------- launcher ----------------------------------------

extern "C" void kernel_launch(void* const* d_in, const int* in_sizes, int n_in,
                              void* d_out, int out_size, void* d_ws,
                              size_t ws_size, hipStream_t stream) {
  (void)in_sizes; (void)n_in; (void)out_size; (void)ws_size;
  const float* emb  = (const float*)d_in[0];
  const float* wih0 = (const float*)d_in[1];
  const float* whh0 = (const float*)d_in[2];
  const float* bih0 = (const float*)d_in[3];
  const float* bhh0 = (const float*)d_in[4];
  const float* wih1 = (const float*)d_in[5];
  const float* whh1 = (const float*)d_in[6];
  const float* bih1 = (const float*)d_in[7];
  const float* bhh1 = (const float*)d_in[8];
  const float* linW = (const float*)d_in[9];
  const float* linb = (const float*)d_in[10];
  const float* outW = (const float*)d_in[11];
  const float* outb = (const float*)d_in[12];
  const int* tokL = (const int*)d_in[13];
  const int* tokR = (const int*)d_in[14];
  const int* lenL = (const int*)d_in[15];
  const int* lenR = (const int*)d_in[16];

  char* ws = (char*)d_ws;
  float* IHBp    = (float*)(ws + OFF_IHB);
  float* B1p     = (float*)(ws + OFF_B1);
  h16* H1p       = (h16*)(ws + OFF_H1);
  h16* H2p       = (h16*)(ws + OFF_H2);
  unsigned* SYp  = (unsigned*)(ws + OFF_SYNC);

  hipMemsetAsync(ws + ZERO_OFF, 0, ZERO_BYTES, stream);  // h state + barrier
  hipMemsetAsync(d_out, 0, 32 * sizeof(float), stream);

  prep_ihb<<<6656, 64, 0, stream>>>(emb, wih0, bih0, bhh0, IHBp);
  prep_bias<<<16, 256, 0, stream>>>(bih1, bhh1, B1p);

  hipFuncSetAttribute((const void*)lstm_main,
                      hipFuncAttributeMaxDynamicSharedMemorySize, LDS_TOTAL);
  void* kargs[] = {(void*)&whh0, (void*)&wih1, (void*)&whh1, (void*)&IHBp,
                   (void*)&B1p,  (void*)&H1p,  (void*)&H2p,  (void*)&SYp,
                   (void*)&tokL, (void*)&tokR, (void*)&lenL, (void*)&lenR};
  hipLaunchCooperativeKernel((const void*)lstm_main, dim3(NWG), dim3(WGT),
                             kargs, (unsigned)LDS_TOTAL, stream);

  head_kernel<<<128, 256, 0, stream>>>(H2p, linW, linb, outW, outb,
                                       (float*)d_out);
}

// Round 5
// 6013.570 us; speedup vs baseline: 1.0273x; 1.0273x over previous
//
#include <hip/hip_runtime.h>

// ---------------------------------------------------------------------------
// TwoHeadLSTM on MI355X — K-split kernel, resubmitted verbatim (rounds 3 & 4
// both died to broker GPUAcquisitionTimeout; this design is still unmeasured).
// Persistent cooperative kernel, 256 WGs x 1024 thr (16 waves/CU, 1 WG/CU).
//  - WG g owns hidden j in [4g,4g+4) for both layers: 16 packed gate-cols of
//    {W_hh0, W_ih1, W_hh1}, staged fp32->f16 into LDS once, layout
//    [m][kk][lane][8] f16 (lane-contiguous per ds_read_b128 -> conflict-free).
//  - K-SPLIT: wave w=(rg,kq) computes 16-row x 16-col x 256-K partials of all
//    3 GEMMs with only 16 up-front global loads/lane (latency fully piped).
//    Partials reduced via padded LDS scratch; waves 0..7 finish the cells.
//  - Per phase p: layer0 t=p and layer1 t=p-1 concurrently; ONE grid barrier.
//  - h state f16 [2][64][1024] double-buffered by parity in workspace.
//  - 2-level barrier, phase-indexed counters + __threadfence release/acquire.
// ---------------------------------------------------------------------------

typedef _Float16 h16;
typedef h16  h16x8 __attribute__((ext_vector_type(8)));
typedef float f32x4 __attribute__((ext_vector_type(4)));

#define NWG 256
#define WGT 1024

// workspace layout (bytes)
#define OFF_IHB   ((size_t)0)         // [256][26][16] f32 = 425984
#define OFF_H1    ((size_t)425984)    // [2][64][1024] f16 = 262144
#define OFF_H2    ((size_t)688128)    // [2][64][1024] f16 = 262144
#define OFF_SYNC  ((size_t)950272)    // [256][64][4] u32  = 262144
#define ZERO_OFF  OFF_H1
#define ZERO_BYTES ((size_t)(262144 + 262144 + 262144))

// LDS: weights 3*32*64*8 f16 = 98304 B; scr 2*4*16*84 f32 = 43008 B;
//      ihbL 26*16 f32 = 1664 B
#define LDS_WB    98304
#define LDS_SCRF  10752               // floats in scr
#define LDS_TOTAL (LDS_WB + 43008 + 1664)

__device__ __forceinline__ float sigm(float x) {
  return 1.0f / (1.0f + __expf(-x));
}
__device__ __forceinline__ float tanh_(float x) {
  float e = __expf(2.0f * x);        // inf-safe: 1 - 2/(e+1)
  return 1.0f - 2.0f / (e + 1.0f);
}

// ------------------------- prep kernel -------------------------------------
// ihb[g][e][c] = emb[e].W_ih0[row(c,g)] + b_ih0[row] + b_hh0[row]
// row(c,g) = (gate<<10) + (g<<2) + jj, gate=c&3, jj=c>>2
__global__ void __launch_bounds__(64) prep_ihb(
    const float* __restrict__ emb, const float* __restrict__ wih0,
    const float* __restrict__ bih0, const float* __restrict__ bhh0,
    float* __restrict__ ihb) {
  int g = blockIdx.x / 26, e = blockIdx.x % 26;
  int l = threadIdx.x, c = l & 15, q = l >> 4;
  int gate = c & 3, jj = c >> 2;
  int row = (gate << 10) + (g << 2) + jj;
  float s = 0.f;
  if (e < 25) {
    const float* er = emb + e * 128 + q * 32;
    const float* wr = wih0 + row * 128 + q * 32;
#pragma unroll
    for (int k = 0; k < 32; k += 4) {
      float4 a = *(const float4*)(er + k);
      float4 b = *(const float4*)(wr + k);
      s += a.x * b.x + a.y * b.y + a.z * b.z + a.w * b.w;
    }
  }
  s += __shfl_xor(s, 16);
  s += __shfl_xor(s, 32);
  if (q == 0) ihb[(g * 26 + e) * 16 + c] = s + bih0[row] + bhh0[row];
}

// ------------------------- grid barrier ------------------------------------
__device__ __forceinline__ void gbar(unsigned* syncb, int p) {
  __syncthreads();                    // drains vmcnt per wave before barrier
  if (threadIdx.x == 0) {
    __threadfence();                  // release: L2 writeback
    unsigned* base = syncb + (size_t)p * 256;
    const int grp = (int)(blockIdx.x >> 5);
    if (__hip_atomic_fetch_add(base + grp * 4, 1u, __ATOMIC_RELAXED,
                               __HIP_MEMORY_SCOPE_AGENT) == 31u) {
      if (__hip_atomic_fetch_add(base + 8 * 4, 1u, __ATOMIC_RELAXED,
                                 __HIP_MEMORY_SCOPE_AGENT) == 7u) {
        __hip_atomic_store(base + 15 * 4, 1u, __ATOMIC_RELEASE,
                           __HIP_MEMORY_SCOPE_AGENT);
      }
    }
    while (__hip_atomic_load(base + 15 * 4, __ATOMIC_RELAXED,
                             __HIP_MEMORY_SCOPE_AGENT) == 0u) {
      __builtin_amdgcn_s_sleep(1);
    }
    __threadfence();                  // acquire: invalidate stale lines
  }
  __syncthreads();
}

// ------------------------- main persistent kernel --------------------------

__global__ void __launch_bounds__(WGT, 1) lstm_main(
    const float* __restrict__ whh0, const float* __restrict__ wih1,
    const float* __restrict__ whh1, const float* __restrict__ ihb,
    const float* __restrict__ bih1, const float* __restrict__ bhh1,
    h16* __restrict__ h1buf, h16* __restrict__ h2buf,
    unsigned* __restrict__ syncb,
    const int* __restrict__ tokL, const int* __restrict__ tokR,
    const int* __restrict__ lenL, const int* __restrict__ lenR) {
  extern __shared__ char lds[];
  h16* wlds = (h16*)lds;                       // [3][32][64][8] f16
  float* scr = (float*)(lds + LDS_WB);         // [(cell*4+rg)*16+m][84]: kq*21+n
  float* ihbL = scr + LDS_SCRF;                // [26][16] f32
  const int g = (int)blockIdx.x;
  const int tid = (int)threadIdx.x;
  const int w = tid >> 6, lane = tid & 63;
  const int rg = w & 3, kq = w >> 2;           // MFMA role: row-group, k-quarter
  const int bl = lane & 15, hi = lane >> 4;

  // ---- stage weights fp32 -> f16 LDS (once); layout [m][kk][lane][8] ----
  for (int ch = tid; ch < 6144; ch += WGT) {
    int m = ch >> 11, rem = ch & 2047, kk = rem >> 6, ln = rem & 63;
    int c = ln & 15, lh = ln >> 4;
    int rowW = ((c & 3) << 10) + (g << 2) + (c >> 2);
    const float* src =
        (m == 0 ? whh0 : (m == 1 ? wih1 : whh1)) + rowW * 1024 + kk * 32 + lh * 8;
    float4 v0 = *(const float4*)(src);
    float4 v1 = *(const float4*)(src + 4);
    h16x8 o;
    o[0] = (h16)v0.x; o[1] = (h16)v0.y; o[2] = (h16)v0.z; o[3] = (h16)v0.w;
    o[4] = (h16)v1.x; o[5] = (h16)v1.y; o[6] = (h16)v1.z; o[7] = (h16)v1.w;
    *(h16x8*)(wlds + (size_t)ch * 8) = o;
  }
  // ---- stage ihb slice into LDS (once) ----
  for (int i = tid; i < 416; i += WGT) ihbL[i] = ihb[g * 416 + i];
  __syncthreads();

  // ---- finisher role (waves 0..7): cell = w>>2, rgF = w&3 ----
  const int mR = lane & 15, jjF = lane >> 4;
  const int rgF = w & 3;
  const int rowF = rgF * 16 + mR;              // batch row 0..63
  const int bF = (rowF < 32) ? rowF : rowF - 32;
  const int* tokF = (rowF < 32) ? tokL : tokR;
  const int lenF = (rowF < 32) ? lenL[bF] : lenR[bF];
  const int jglob = (g << 2) + jjF;
  f32x4 bb;
#pragma unroll
  for (int q = 0; q < 4; ++q) {
    int rowW = q * 1024 + (g << 2) + jjF;
    bb[q] = bih1[rowW] + bhh1[rowW];
  }

  float c1 = 0.f, h1v = 0.f, c2 = 0.f, h2v = 0.f;

  for (int p = 0; p <= 256; ++p) {
    const int r = p & 1;
    // ---- issue ALL 16 A-frag loads up front (64 landing VGPRs) ----
    const h16* a1p = h1buf + r * 65536 + (rg * 16 + bl) * 1024 + kq * 256 + hi * 8;
    const h16* a2p = h2buf + (r ^ 1) * 65536 + (rg * 16 + bl) * 1024 + kq * 256 + hi * 8;
    h16x8 A1[8], A2[8];
#pragma unroll
    for (int i = 0; i < 8; ++i) A1[i] = *(const h16x8*)(a1p + i * 32);
#pragma unroll
    for (int i = 0; i < 8; ++i) A2[i] = *(const h16x8*)(a2p + i * 32);

    // token load (cell0 finishers), independent of A loads
    int e = 25;
    if (w < 4 && p < 256) {
      int tok = tokF[p * 32 + bF];
      e = (tok < 0) ? 25 : tok;
    }

    f32x4 acc0 = {0.f, 0.f, 0.f, 0.f};
    f32x4 acca = {0.f, 0.f, 0.f, 0.f};
    f32x4 accb = {0.f, 0.f, 0.f, 0.f};
#pragma unroll
    for (int i = 0; i < 8; ++i) {
      int kk = kq * 8 + i;
      h16x8 b0 = *(const h16x8*)(wlds + ((size_t)(0 * 32 + kk) * 64 + lane) * 8);
      h16x8 b1 = *(const h16x8*)(wlds + ((size_t)(1 * 32 + kk) * 64 + lane) * 8);
      h16x8 b2 = *(const h16x8*)(wlds + ((size_t)(2 * 32 + kk) * 64 + lane) * 8);
      acc0 = __builtin_amdgcn_mfma_f32_16x16x32_f16(A1[i], b0, acc0, 0, 0, 0);
      acca = __builtin_amdgcn_mfma_f32_16x16x32_f16(A1[i], b1, acca, 0, 0, 0);
      accb = __builtin_amdgcn_mfma_f32_16x16x32_f16(A2[i], b2, accb, 0, 0, 0);
    }
    f32x4 s1 = acca + accb;

    // ---- write partials: D[m=hi*4+q][n] -> scr[(cell*4+rg)*16+m][kq*21+n] ----
#pragma unroll
    for (int q = 0; q < 4; ++q) {
      int m = (hi << 2) + q;
      scr[((0 + rg) * 16 + m) * 84 + kq * 21 + bl] = acc0[q];
      scr[((4 + rg) * 16 + m) * 84 + kq * 21 + bl] = s1[q];
    }
    __syncthreads();

    // ---- finish: waves 0..7 (w == cell*4+rgF), 512 threads ----
    if (w < 8) {
      const bool cell0 = (w < 4);
      if ((cell0 && p < 256) || (!cell0 && p >= 1)) {
        const float* sb = scr + ((size_t)w * 16 + mR) * 84 + (jjF << 2);
        f32x4 gv = {0.f, 0.f, 0.f, 0.f};
#pragma unroll
        for (int k2 = 0; k2 < 4; ++k2) gv += *(const f32x4*)(sb + k2 * 21);
        if (cell0) {
          f32x4 ib = *(const f32x4*)(ihbL + (e << 4) + (jjF << 2));
          float gi = gv[0] + ib[0], gf = gv[1] + ib[1];
          float gg = gv[2] + ib[2], go = gv[3] + ib[3];
          if (p < lenF) {
            float iv = sigm(gi), fv = sigm(gf), gt = tanh_(gg), ov = sigm(go);
            c1 = fv * c1 + iv * gt;
            h1v = ov * tanh_(c1);
          }
          h1buf[(r ^ 1) * 65536 + rowF * 1024 + jglob] = (h16)h1v;
        } else {
          float gi = gv[0] + bb[0], gf = gv[1] + bb[1];
          float gg = gv[2] + bb[2], go = gv[3] + bb[3];
          if (p - 1 < lenF) {
            float iv = sigm(gi), fv = sigm(gf), gt = tanh_(gg), ov = sigm(go);
            c2 = fv * c2 + iv * gt;
            h2v = ov * tanh_(c2);
          }
          h2buf[r * 65536 + rowF * 1024 + jglob] = (h16)h2v;
        }
      }
    }

    if (p < 256) gbar(syncb, p);
  }
  // final h2 (t=255) lives in h2buf slot 0
}

// ------------------------- head (lin+relu+out) -----------------------------

__global__ void __launch_bounds__(256) head_kernel(
    const h16* __restrict__ h2, const float* __restrict__ linW,
    const float* __restrict__ linb, const float* __restrict__ outW,
    const float* __restrict__ outb, float* __restrict__ out) {
  __shared__ h16 hl[2048];
  __shared__ float red[4];
  const int b = (int)blockIdx.x >> 2, lq = (int)blockIdx.x & 3;
  const int tid = (int)threadIdx.x;
  {
    int k0 = tid * 8;
    const h16* src = (k0 < 1024) ? (h2 + b * 1024 + k0)
                                 : (h2 + (b + 32) * 1024 + (k0 - 1024));
    *(h16x8*)(hl + k0) = *(const h16x8*)src;
  }
  __syncthreads();
  const int l = lq * 256 + tid;
  float acc = linb[l];
  const float* wr = linW + (size_t)l * 2048;
  for (int k = 0; k < 2048; k += 4) {
    float4 wv = *(const float4*)(wr + k);
    acc += wv.x * (float)hl[k] + wv.y * (float)hl[k + 1] +
           wv.z * (float)hl[k + 2] + wv.w * (float)hl[k + 3];
  }
  float v = fmaxf(acc, 0.f) * outW[l];
  for (int off = 32; off > 0; off >>= 1) v += __shfl_down(v, off);
  if ((tid & 63) == 0) red[tid >> 6] = v;
  __syncthreads();
  if (tid == 0) {
    float s = red[0] + red[1] + red[2] + red[3];
    if (lq == 0) s += outb[0];
    atomicAdd(out + b, s);
  }
}

// ------------------------- launcher ----------------------------------------

extern "C" void kernel_launch(void* const* d_in, const int* in_sizes, int n_in,
                              void* d_out, int out_size, void* d_ws,
                              size_t ws_size, hipStream_t stream) {
  (void)in_sizes; (void)n_in; (void)out_size; (void)ws_size;
  const float* emb  = (const float*)d_in[0];
  const float* wih0 = (const float*)d_in[1];
  const float* whh0 = (const float*)d_in[2];
  const float* bih0 = (const float*)d_in[3];
  const float* bhh0 = (const float*)d_in[4];
  const float* wih1 = (const float*)d_in[5];
  const float* whh1 = (const float*)d_in[6];
  const float* bih1 = (const float*)d_in[7];
  const float* bhh1 = (const float*)d_in[8];
  const float* linW = (const float*)d_in[9];
  const float* linb = (const float*)d_in[10];
  const float* outW = (const float*)d_in[11];
  const float* outb = (const float*)d_in[12];
  const int* tokL = (const int*)d_in[13];
  const int* tokR = (const int*)d_in[14];
  const int* lenL = (const int*)d_in[15];
  const int* lenR = (const int*)d_in[16];

  char* ws = (char*)d_ws;
  float* IHBp    = (float*)(ws + OFF_IHB);
  h16* H1p       = (h16*)(ws + OFF_H1);
  h16* H2p       = (h16*)(ws + OFF_H2);
  unsigned* SYp  = (unsigned*)(ws + OFF_SYNC);

  hipMemsetAsync(ws + ZERO_OFF, 0, ZERO_BYTES, stream);  // h state + barrier
  hipMemsetAsync(d_out, 0, 32 * sizeof(float), stream);

  prep_ihb<<<6656, 64, 0, stream>>>(emb, wih0, bih0, bhh0, IHBp);

  hipFuncSetAttribute((const void*)lstm_main,
                      hipFuncAttributeMaxDynamicSharedMemorySize, LDS_TOTAL);
  void* kargs[] = {(void*)&whh0, (void*)&wih1, (void*)&whh1, (void*)&IHBp,
                   (void*)&bih1, (void*)&bhh1, (void*)&H1p,  (void*)&H2p,
                   (void*)&SYp,  (void*)&tokL, (void*)&tokR, (void*)&lenL,
                   (void*)&lenR};
  hipLaunchCooperativeKernel((const void*)lstm_main, dim3(NWG), dim3(WGT),
                             kargs, (unsigned)LDS_TOTAL, stream);

  head_kernel<<<128, 256, 0, stream>>>(H2p, linW, linb, outW, outb,
                                       (float*)d_out);
}

// Round 6
// 3764.336 us; speedup vs baseline: 1.6412x; 1.5975x over previous
//
#include <hip/hip_runtime.h>

// ---------------------------------------------------------------------------
// TwoHeadLSTM on MI355X — round 6: remove __threadfence() L2-maintenance ops.
// Theory: both prior designs pinned at ~23us/phase because each phase's grid
// barrier did agent fences (buffer_wbl2/buffer_inv bulk L2 ops) from 256 WG
// leaders. Replace with per-access coherence: h1/h2 exchanged via sc0 sc1
// (system-coherent) loads/stores that bypass L2, plus explicit vmcnt(0) drain
// before the barrier arrive. Barrier atomics stay relaxed/agent (proven to
// propagate cross-XCD in rounds 2/5). Everything else identical to round 5.
// ---------------------------------------------------------------------------

typedef _Float16 h16;
typedef h16  h16x8 __attribute__((ext_vector_type(8)));
typedef float f32x4 __attribute__((ext_vector_type(4)));

#define NWG 256
#define WGT 1024

// workspace layout (bytes)
#define OFF_IHB   ((size_t)0)         // [256][26][16] f32 = 425984
#define OFF_H1    ((size_t)425984)    // [2][64][1024] f16 = 262144
#define OFF_H2    ((size_t)688128)    // [2][64][1024] f16 = 262144
#define OFF_SYNC  ((size_t)950272)    // [256][64][4] u32  = 262144
#define ZERO_OFF  OFF_H1
#define ZERO_BYTES ((size_t)(262144 + 262144 + 262144))

// LDS: weights 3*32*64*8 f16 = 98304 B; scr 2*4*16*84 f32 = 43008 B;
//      ihbL 26*16 f32 = 1664 B
#define LDS_WB    98304
#define LDS_SCRF  10752               // floats in scr
#define LDS_TOTAL (LDS_WB + 43008 + 1664)

// system-coherent 16B load: bypasses L1/L2, served at the coherence point
// (memory-side Infinity Cache) -> always fresh across XCDs, no fences needed.
#define LDG_SC(dst, base, OFFB)                                          \
  asm volatile("global_load_dwordx4 %0, %1, off offset:" #OFFB " sc0 sc1" \
               : "=v"(dst) : "v"(base))

__device__ __forceinline__ void stg_sc_h16(h16* p, float v) {
  union { h16 h; unsigned short u; } cv;
  cv.h = (h16)v;
  unsigned vv = cv.u;
  asm volatile("global_store_short %0, %1, off sc0 sc1"
               :: "v"(p), "v"(vv) : "memory");
}

__device__ __forceinline__ float sigm(float x) {
  return 1.0f / (1.0f + __expf(-x));
}
__device__ __forceinline__ float tanh_(float x) {
  float e = __expf(2.0f * x);        // inf-safe: 1 - 2/(e+1)
  return 1.0f - 2.0f / (e + 1.0f);
}

// ------------------------- prep kernel -------------------------------------
// ihb[g][e][c] = emb[e].W_ih0[row(c,g)] + b_ih0[row] + b_hh0[row]
// row(c,g) = (gate<<10) + (g<<2) + jj, gate=c&3, jj=c>>2
__global__ void __launch_bounds__(64) prep_ihb(
    const float* __restrict__ emb, const float* __restrict__ wih0,
    const float* __restrict__ bih0, const float* __restrict__ bhh0,
    float* __restrict__ ihb) {
  int g = blockIdx.x / 26, e = blockIdx.x % 26;
  int l = threadIdx.x, c = l & 15, q = l >> 4;
  int gate = c & 3, jj = c >> 2;
  int row = (gate << 10) + (g << 2) + jj;
  float s = 0.f;
  if (e < 25) {
    const float* er = emb + e * 128 + q * 32;
    const float* wr = wih0 + row * 128 + q * 32;
#pragma unroll
    for (int k = 0; k < 32; k += 4) {
      float4 a = *(const float4*)(er + k);
      float4 b = *(const float4*)(wr + k);
      s += a.x * b.x + a.y * b.y + a.z * b.z + a.w * b.w;
    }
  }
  s += __shfl_xor(s, 16);
  s += __shfl_xor(s, 32);
  if (q == 0) ihb[(g * 26 + e) * 16 + c] = s + bih0[row] + bhh0[row];
}

// ------------------------- grid barrier ------------------------------------
// NO __threadfence: data visibility comes from sc0/sc1 accesses + the
// vmcnt(0) drain below (sc stores ack from the coherence point).
__device__ __forceinline__ void gbar(unsigned* syncb, int p) {
  asm volatile("s_waitcnt vmcnt(0)" ::: "memory");  // drain asm sc-stores
  __syncthreads();
  if (threadIdx.x == 0) {
    unsigned* base = syncb + (size_t)p * 256;
    const int grp = (int)(blockIdx.x >> 5);
    if (__hip_atomic_fetch_add(base + grp * 4, 1u, __ATOMIC_RELAXED,
                               __HIP_MEMORY_SCOPE_AGENT) == 31u) {
      if (__hip_atomic_fetch_add(base + 8 * 4, 1u, __ATOMIC_RELAXED,
                                 __HIP_MEMORY_SCOPE_AGENT) == 7u) {
        __hip_atomic_store(base + 15 * 4, 1u, __ATOMIC_RELAXED,
                           __HIP_MEMORY_SCOPE_AGENT);
      }
    }
    while (__hip_atomic_load(base + 15 * 4, __ATOMIC_RELAXED,
                             __HIP_MEMORY_SCOPE_AGENT) == 0u) {
      __builtin_amdgcn_s_sleep(1);
    }
  }
  __syncthreads();
  asm volatile("" ::: "memory");      // keep next-phase asm loads below here
}

// ------------------------- main persistent kernel --------------------------

__global__ void __launch_bounds__(WGT, 1) lstm_main(
    const float* __restrict__ whh0, const float* __restrict__ wih1,
    const float* __restrict__ whh1, const float* __restrict__ ihb,
    const float* __restrict__ bih1, const float* __restrict__ bhh1,
    h16* __restrict__ h1buf, h16* __restrict__ h2buf,
    unsigned* __restrict__ syncb,
    const int* __restrict__ tokL, const int* __restrict__ tokR,
    const int* __restrict__ lenL, const int* __restrict__ lenR) {
  extern __shared__ char lds[];
  h16* wlds = (h16*)lds;                       // [3][32][64][8] f16
  float* scr = (float*)(lds + LDS_WB);         // [(cell*4+rg)*16+m][84]: kq*21+n
  float* ihbL = scr + LDS_SCRF;                // [26][16] f32
  const int g = (int)blockIdx.x;
  const int tid = (int)threadIdx.x;
  const int w = tid >> 6, lane = tid & 63;
  const int rg = w & 3, kq = w >> 2;           // MFMA role: row-group, k-quarter
  const int bl = lane & 15, hi = lane >> 4;

  // ---- stage weights fp32 -> f16 LDS (once); layout [m][kk][lane][8] ----
  for (int ch = tid; ch < 6144; ch += WGT) {
    int m = ch >> 11, rem = ch & 2047, kk = rem >> 6, ln = rem & 63;
    int c = ln & 15, lh = ln >> 4;
    int rowW = ((c & 3) << 10) + (g << 2) + (c >> 2);
    const float* src =
        (m == 0 ? whh0 : (m == 1 ? wih1 : whh1)) + rowW * 1024 + kk * 32 + lh * 8;
    float4 v0 = *(const float4*)(src);
    float4 v1 = *(const float4*)(src + 4);
    h16x8 o;
    o[0] = (h16)v0.x; o[1] = (h16)v0.y; o[2] = (h16)v0.z; o[3] = (h16)v0.w;
    o[4] = (h16)v1.x; o[5] = (h16)v1.y; o[6] = (h16)v1.z; o[7] = (h16)v1.w;
    *(h16x8*)(wlds + (size_t)ch * 8) = o;
  }
  // ---- stage ihb slice into LDS (once) ----
  for (int i = tid; i < 416; i += WGT) ihbL[i] = ihb[g * 416 + i];
  __syncthreads();

  // ---- finisher role (waves 0..7): cell = w>>2, rgF = w&3 ----
  const int mR = lane & 15, jjF = lane >> 4;
  const int rgF = w & 3;
  const int rowF = rgF * 16 + mR;              // batch row 0..63
  const int bF = (rowF < 32) ? rowF : rowF - 32;
  const int* tokF = (rowF < 32) ? tokL : tokR;
  const int lenF = (rowF < 32) ? lenL[bF] : lenR[bF];
  const int jglob = (g << 2) + jjF;
  f32x4 bb;
#pragma unroll
  for (int q = 0; q < 4; ++q) {
    int rowW = q * 1024 + (g << 2) + jjF;
    bb[q] = bih1[rowW] + bhh1[rowW];
  }

  float c1 = 0.f, h1v = 0.f, c2 = 0.f, h2v = 0.f;

  for (int p = 0; p <= 256; ++p) {
    const int r = p & 1;
    // ---- issue ALL 16 A-frag sc-loads up front (bypass L1/L2, fresh) ----
    const h16* a1p = h1buf + r * 65536 + (rg * 16 + bl) * 1024 + kq * 256 + hi * 8;
    const h16* a2p = h2buf + (r ^ 1) * 65536 + (rg * 16 + bl) * 1024 + kq * 256 + hi * 8;
    f32x4 A1r[8], A2r[8];
    LDG_SC(A1r[0], a1p, 0);   LDG_SC(A1r[1], a1p, 64);
    LDG_SC(A1r[2], a1p, 128); LDG_SC(A1r[3], a1p, 192);
    LDG_SC(A1r[4], a1p, 256); LDG_SC(A1r[5], a1p, 320);
    LDG_SC(A1r[6], a1p, 384); LDG_SC(A1r[7], a1p, 448);
    LDG_SC(A2r[0], a2p, 0);   LDG_SC(A2r[1], a2p, 64);
    LDG_SC(A2r[2], a2p, 128); LDG_SC(A2r[3], a2p, 192);
    LDG_SC(A2r[4], a2p, 256); LDG_SC(A2r[5], a2p, 320);
    LDG_SC(A2r[6], a2p, 384); LDG_SC(A2r[7], a2p, 448);

    // token load (cell0 finishers): immutable input, normal cached load
    int e = 25;
    if (w < 4 && p < 256) {
      int tok = tokF[p * 32 + bF];
      e = (tok < 0) ? 25 : tok;
    }

    asm volatile("s_waitcnt vmcnt(0)" ::: "memory");  // asm loads untracked
    __builtin_amdgcn_sched_barrier(0);

    f32x4 acc0 = {0.f, 0.f, 0.f, 0.f};
    f32x4 acca = {0.f, 0.f, 0.f, 0.f};
    f32x4 accb = {0.f, 0.f, 0.f, 0.f};
#pragma unroll
    for (int i = 0; i < 8; ++i) {
      int kk = kq * 8 + i;
      h16x8 a1 = __builtin_bit_cast(h16x8, A1r[i]);
      h16x8 a2 = __builtin_bit_cast(h16x8, A2r[i]);
      h16x8 b0 = *(const h16x8*)(wlds + ((size_t)(0 * 32 + kk) * 64 + lane) * 8);
      h16x8 b1 = *(const h16x8*)(wlds + ((size_t)(1 * 32 + kk) * 64 + lane) * 8);
      h16x8 b2 = *(const h16x8*)(wlds + ((size_t)(2 * 32 + kk) * 64 + lane) * 8);
      acc0 = __builtin_amdgcn_mfma_f32_16x16x32_f16(a1, b0, acc0, 0, 0, 0);
      acca = __builtin_amdgcn_mfma_f32_16x16x32_f16(a1, b1, acca, 0, 0, 0);
      accb = __builtin_amdgcn_mfma_f32_16x16x32_f16(a2, b2, accb, 0, 0, 0);
    }
    f32x4 s1 = acca + accb;

    // ---- write partials: D[m=hi*4+q][n] -> scr[(cell*4+rg)*16+m][kq*21+n] ----
#pragma unroll
    for (int q = 0; q < 4; ++q) {
      int m = (hi << 2) + q;
      scr[((0 + rg) * 16 + m) * 84 + kq * 21 + bl] = acc0[q];
      scr[((4 + rg) * 16 + m) * 84 + kq * 21 + bl] = s1[q];
    }
    __syncthreads();

    // ---- finish: waves 0..7 (w == cell*4+rgF), 512 threads ----
    if (w < 8) {
      const bool cell0 = (w < 4);
      if ((cell0 && p < 256) || (!cell0 && p >= 1)) {
        const float* sb = scr + ((size_t)w * 16 + mR) * 84 + (jjF << 2);
        f32x4 gv = {0.f, 0.f, 0.f, 0.f};
#pragma unroll
        for (int k2 = 0; k2 < 4; ++k2) gv += *(const f32x4*)(sb + k2 * 21);
        if (cell0) {
          f32x4 ib = *(const f32x4*)(ihbL + (e << 4) + (jjF << 2));
          float gi = gv[0] + ib[0], gf = gv[1] + ib[1];
          float gg = gv[2] + ib[2], go = gv[3] + ib[3];
          if (p < lenF) {
            float iv = sigm(gi), fv = sigm(gf), gt = tanh_(gg), ov = sigm(go);
            c1 = fv * c1 + iv * gt;
            h1v = ov * tanh_(c1);
          }
          stg_sc_h16(h1buf + (r ^ 1) * 65536 + rowF * 1024 + jglob, h1v);
        } else {
          float gi = gv[0] + bb[0], gf = gv[1] + bb[1];
          float gg = gv[2] + bb[2], go = gv[3] + bb[3];
          if (p - 1 < lenF) {
            float iv = sigm(gi), fv = sigm(gf), gt = tanh_(gg), ov = sigm(go);
            c2 = fv * c2 + iv * gt;
            h2v = ov * tanh_(c2);
          }
          stg_sc_h16(h2buf + r * 65536 + rowF * 1024 + jglob, h2v);
        }
      }
    }

    if (p < 256) gbar(syncb, p);
  }
  // final h2 (t=255) lives in h2buf slot 0 (sc stores are at the coherence
  // point; kernel-boundary flush makes them visible to head_kernel)
}

// ------------------------- head (lin+relu+out) -----------------------------

__global__ void __launch_bounds__(256) head_kernel(
    const h16* __restrict__ h2, const float* __restrict__ linW,
    const float* __restrict__ linb, const float* __restrict__ outW,
    const float* __restrict__ outb, float* __restrict__ out) {
  __shared__ h16 hl[2048];
  __shared__ float red[4];
  const int b = (int)blockIdx.x >> 2, lq = (int)blockIdx.x & 3;
  const int tid = (int)threadIdx.x;
  {
    int k0 = tid * 8;
    const h16* src = (k0 < 1024) ? (h2 + b * 1024 + k0)
                                 : (h2 + (b + 32) * 1024 + (k0 - 1024));
    *(h16x8*)(hl + k0) = *(const h16x8*)src;
  }
  __syncthreads();
  const int l = lq * 256 + tid;
  float acc = linb[l];
  const float* wr = linW + (size_t)l * 2048;
  for (int k = 0; k < 2048; k += 4) {
    float4 wv = *(const float4*)(wr + k);
    acc += wv.x * (float)hl[k] + wv.y * (float)hl[k + 1] +
           wv.z * (float)hl[k + 2] + wv.w * (float)hl[k + 3];
  }
  float v = fmaxf(acc, 0.f) * outW[l];
  for (int off = 32; off > 0; off >>= 1) v += __shfl_down(v, off);
  if ((tid & 63) == 0) red[tid >> 6] = v;
  __syncthreads();
  if (tid == 0) {
    float s = red[0] + red[1] + red[2] + red[3];
    if (lq == 0) s += outb[0];
    atomicAdd(out + b, s);
  }
}

// ------------------------- launcher ----------------------------------------

extern "C" void kernel_launch(void* const* d_in, const int* in_sizes, int n_in,
                              void* d_out, int out_size, void* d_ws,
                              size_t ws_size, hipStream_t stream) {
  (void)in_sizes; (void)n_in; (void)out_size; (void)ws_size;
  const float* emb  = (const float*)d_in[0];
  const float* wih0 = (const float*)d_in[1];
  const float* whh0 = (const float*)d_in[2];
  const float* bih0 = (const float*)d_in[3];
  const float* bhh0 = (const float*)d_in[4];
  const float* wih1 = (const float*)d_in[5];
  const float* whh1 = (const float*)d_in[6];
  const float* bih1 = (const float*)d_in[7];
  const float* bhh1 = (const float*)d_in[8];
  const float* linW = (const float*)d_in[9];
  const float* linb = (const float*)d_in[10];
  const float* outW = (const float*)d_in[11];
  const float* outb = (const float*)d_in[12];
  const int* tokL = (const int*)d_in[13];
  const int* tokR = (const int*)d_in[14];
  const int* lenL = (const int*)d_in[15];
  const int* lenR = (const int*)d_in[16];

  char* ws = (char*)d_ws;
  float* IHBp    = (float*)(ws + OFF_IHB);
  h16* H1p       = (h16*)(ws + OFF_H1);
  h16* H2p       = (h16*)(ws + OFF_H2);
  unsigned* SYp  = (unsigned*)(ws + OFF_SYNC);

  hipMemsetAsync(ws + ZERO_OFF, 0, ZERO_BYTES, stream);  // h state + barrier
  hipMemsetAsync(d_out, 0, 32 * sizeof(float), stream);

  prep_ihb<<<6656, 64, 0, stream>>>(emb, wih0, bih0, bhh0, IHBp);

  hipFuncSetAttribute((const void*)lstm_main,
                      hipFuncAttributeMaxDynamicSharedMemorySize, LDS_TOTAL);
  void* kargs[] = {(void*)&whh0, (void*)&wih1, (void*)&whh1, (void*)&IHBp,
                   (void*)&bih1, (void*)&bhh1, (void*)&H1p,  (void*)&H2p,
                   (void*)&SYp,  (void*)&tokL, (void*)&tokR, (void*)&lenL,
                   (void*)&lenR};
  hipLaunchCooperativeKernel((const void*)lstm_main, dim3(NWG), dim3(WGT),
                             kargs, (unsigned)LDS_TOTAL, stream);

  head_kernel<<<128, 256, 0, stream>>>(H2p, linW, linb, outW, outb,
                                       (float*)d_out);
}

// Round 7
// 3716.686 us; speedup vs baseline: 1.6622x; 1.0128x over previous
//
#include <hip/hip_runtime.h>

// ---------------------------------------------------------------------------
// TwoHeadLSTM on MI355X — round 7: role-split WGs to cut IC broadcast 25%.
// 256 WGs x 512 thr (8 waves). WGs 0..127 = layer0 role (owns 8 j's of W_hh0,
// 64KB LDS, reads h1 only = 128KB/phase); WGs 128..255 = layer1 role (owns
// 8 j's of W_ih1+W_hh1, 128KB LDS, reads h1+h2 = 256KB/phase).
// Chip broadcast 64 -> 48 MB/phase. Everything else as round 6 (proven):
// sc0/sc1 IC-coherent h exchange, fence-free phase-indexed barrier,
// layer1 pipelined one step behind layer0, ONE grid barrier per phase.
// ---------------------------------------------------------------------------

typedef _Float16 h16;
typedef h16  h16x8 __attribute__((ext_vector_type(8)));
typedef float f32x4 __attribute__((ext_vector_type(4)));

#define NWG 256
#define WGT 512

// workspace layout (bytes)
#define OFF_IHB   ((size_t)0)         // [128][26][32] f32 = 425984
#define OFF_H1    ((size_t)425984)    // [2][64][1024] f16 = 262144
#define OFF_H2    ((size_t)688128)    // [2][64][1024] f16 = 262144
#define OFF_SYNC  ((size_t)950272)    // [256][64][4] u32  = 262144
#define ZERO_OFF  OFF_H1
#define ZERO_BYTES ((size_t)(262144 + 262144 + 262144))

// LDS: weights (L1 max) 2*2*32*64*8 f16 = 131072; scr [2][64][36] f32 = 18432;
//      ihb (L0 only) [26][32] f32 = 3328
#define LDS_WOFF  0
#define LDS_SOFF  131072
#define LDS_IOFF  (131072 + 18432)
#define LDS_TOTAL (131072 + 18432 + 3328)

// system-coherent 16B load: bypasses L1/L2, served at the IC (coherence pt)
#define LDG_SC(dst, base, OFFB)                                          \
  asm volatile("global_load_dwordx4 %0, %1, off offset:" #OFFB " sc0 sc1" \
               : "=v"(dst) : "v"(base))

__device__ __forceinline__ void stg_sc_h16(h16* p, float v) {
  union { h16 h; unsigned short u; } cv;
  cv.h = (h16)v;
  unsigned vv = cv.u;
  asm volatile("global_store_short %0, %1, off sc0 sc1"
               :: "v"(p), "v"(vv) : "memory");
}

__device__ __forceinline__ float sigm(float x) {
  return 1.0f / (1.0f + __expf(-x));
}
__device__ __forceinline__ float tanh_(float x) {
  float e = __expf(2.0f * x);
  return 1.0f - 2.0f / (e + 1.0f);
}

// ------------------------- prep kernel -------------------------------------
// ihb[g][e][c] = emb[e].W_ih0[row] + b_ih0[row] + b_hh0[row]
// g in [0,128): 8 j's each; c in [0,32): gate=c&3, jj=c>>2, row=gate*1024+g*8+jj
__global__ void __launch_bounds__(64) prep_ihb(
    const float* __restrict__ emb, const float* __restrict__ wih0,
    const float* __restrict__ bih0, const float* __restrict__ bhh0,
    float* __restrict__ ihb) {
  int g = blockIdx.x / 26, e = blockIdx.x % 26;
  int l = threadIdx.x, c = l & 31, q = l >> 5;
  int gate = c & 3, jj = c >> 2;
  int row = (gate << 10) + g * 8 + jj;
  float s = 0.f;
  if (e < 25) {
    const float* er = emb + e * 128 + q * 64;
    const float* wr = wih0 + row * 128 + q * 64;
#pragma unroll
    for (int k = 0; k < 64; k += 4) {
      float4 a = *(const float4*)(er + k);
      float4 b = *(const float4*)(wr + k);
      s += a.x * b.x + a.y * b.y + a.z * b.z + a.w * b.w;
    }
  }
  s += __shfl_xor(s, 32);
  if (q == 0) ihb[(g * 26 + e) * 32 + c] = s + bih0[row] + bhh0[row];
}

// ------------------------- grid barrier (round-6 proven, fence-free) -------
__device__ __forceinline__ void gbar(unsigned* syncb, int p) {
  asm volatile("s_waitcnt vmcnt(0)" ::: "memory");  // drain asm sc-stores
  __syncthreads();
  if (threadIdx.x == 0) {
    unsigned* base = syncb + (size_t)p * 256;
    const int grp = (int)(blockIdx.x >> 5);
    if (__hip_atomic_fetch_add(base + grp * 4, 1u, __ATOMIC_RELAXED,
                               __HIP_MEMORY_SCOPE_AGENT) == 31u) {
      if (__hip_atomic_fetch_add(base + 8 * 4, 1u, __ATOMIC_RELAXED,
                                 __HIP_MEMORY_SCOPE_AGENT) == 7u) {
        __hip_atomic_store(base + 15 * 4, 1u, __ATOMIC_RELAXED,
                           __HIP_MEMORY_SCOPE_AGENT);
      }
    }
    while (__hip_atomic_load(base + 15 * 4, __ATOMIC_RELAXED,
                             __HIP_MEMORY_SCOPE_AGENT) == 0u) {
      __builtin_amdgcn_s_sleep(1);
    }
  }
  __syncthreads();
  asm volatile("" ::: "memory");
}

// ------------------------- main persistent kernel --------------------------

__global__ void __launch_bounds__(WGT, 2) lstm_main(
    const float* __restrict__ whh0, const float* __restrict__ wih1,
    const float* __restrict__ whh1, const float* __restrict__ ihb,
    const float* __restrict__ bih1, const float* __restrict__ bhh1,
    h16* __restrict__ h1buf, h16* __restrict__ h2buf,
    unsigned* __restrict__ syncb,
    const int* __restrict__ tokL, const int* __restrict__ tokR,
    const int* __restrict__ lenL, const int* __restrict__ lenR) {
  extern __shared__ char lds[];
  h16* wlds = (h16*)(lds + LDS_WOFF);   // [mats][nt][32 kk][64 ln][8] f16
  float* scr = (float*)(lds + LDS_SOFF); // [2 kq][64 row][36] f32
  float* ihbL = (float*)(lds + LDS_IOFF);// [26][32] f32 (L0 only)
  const int bid = (int)blockIdx.x;
  const int role = bid >> 7;            // 0: layer0, 1: layer1
  const int og = bid & 127;             // j-group: j in [8*og, 8*og+8)
  const int tid = (int)threadIdx.x;
  const int wv = tid >> 6, lane = tid & 63;
  const int rg = wv & 3, kq = wv >> 2;  // rows 16*rg, k-half 512*kq
  const int bl = lane & 15, hi = lane >> 4;

  // ---- stage weights fp32 -> f16 LDS (once) ----
  const int nch = role ? 8192 : 4096;   // chunks of 8 f16
  for (int ch = tid; ch < nch; ch += WGT) {
    int m = ch >> 12, nt = (ch >> 11) & 1, kk = (ch >> 6) & 31, ln = ch & 63;
    int c = nt * 16 + (ln & 15), ksub = ln >> 4;
    int row = ((c & 3) << 10) + og * 8 + (c >> 2);
    const float* wsrc = role ? (m ? whh1 : wih1) : whh0;
    const float* src = wsrc + row * 1024 + kk * 32 + ksub * 8;
    float4 v0 = *(const float4*)(src);
    float4 v1 = *(const float4*)(src + 4);
    h16x8 o;
    o[0] = (h16)v0.x; o[1] = (h16)v0.y; o[2] = (h16)v0.z; o[3] = (h16)v0.w;
    o[4] = (h16)v1.x; o[5] = (h16)v1.y; o[6] = (h16)v1.z; o[7] = (h16)v1.w;
    *(h16x8*)(wlds + (size_t)ch * 8) = o;
  }
  if (!role) {                          // stage ihb slice (once)
    for (int i = tid; i < 832; i += WGT) ihbL[i] = ihb[og * 832 + i];
  }
  __syncthreads();

  // ---- finisher identity: thread = (row=lane, j=wv) ----
  const int rowF = lane;                // batch row 0..63
  const int jF = wv;                    // j-in-group 0..7
  const int bF = (rowF < 32) ? rowF : rowF - 32;
  const int* tokF = (rowF < 32) ? tokL : tokR;
  const int lenF = (rowF < 32) ? lenL[bF] : lenR[bF];
  const int jglob = og * 8 + jF;
  f32x4 bb = {0.f, 0.f, 0.f, 0.f};
  if (role) {
#pragma unroll
    for (int q = 0; q < 4; ++q) {
      int row = (q << 10) + jglob;
      bb[q] = bih1[row] + bhh1[row];
    }
  }

  float cs = 0.f, hv = 0.f;             // cell/hidden state for this thread

  for (int p = 0; p <= 256; ++p) {
    const int r = p & 1;
    const size_t abase = (size_t)(rg * 16 + bl) * 1024 + kq * 512 + hi * 8;
    const h16* a1p = h1buf + r * 65536 + abase;

    f32x4 A1r[16];
    LDG_SC(A1r[0],  a1p, 0);   LDG_SC(A1r[1],  a1p, 64);
    LDG_SC(A1r[2],  a1p, 128); LDG_SC(A1r[3],  a1p, 192);
    LDG_SC(A1r[4],  a1p, 256); LDG_SC(A1r[5],  a1p, 320);
    LDG_SC(A1r[6],  a1p, 384); LDG_SC(A1r[7],  a1p, 448);
    LDG_SC(A1r[8],  a1p, 512); LDG_SC(A1r[9],  a1p, 576);
    LDG_SC(A1r[10], a1p, 640); LDG_SC(A1r[11], a1p, 704);
    LDG_SC(A1r[12], a1p, 768); LDG_SC(A1r[13], a1p, 832);
    LDG_SC(A1r[14], a1p, 896); LDG_SC(A1r[15], a1p, 960);

    f32x4 A2r[16];
    if (role) {
      const h16* a2p = h2buf + (r ^ 1) * 65536 + abase;
      LDG_SC(A2r[0],  a2p, 0);   LDG_SC(A2r[1],  a2p, 64);
      LDG_SC(A2r[2],  a2p, 128); LDG_SC(A2r[3],  a2p, 192);
      LDG_SC(A2r[4],  a2p, 256); LDG_SC(A2r[5],  a2p, 320);
      LDG_SC(A2r[6],  a2p, 384); LDG_SC(A2r[7],  a2p, 448);
      LDG_SC(A2r[8],  a2p, 512); LDG_SC(A2r[9],  a2p, 576);
      LDG_SC(A2r[10], a2p, 640); LDG_SC(A2r[11], a2p, 704);
      LDG_SC(A2r[12], a2p, 768); LDG_SC(A2r[13], a2p, 832);
      LDG_SC(A2r[14], a2p, 896); LDG_SC(A2r[15], a2p, 960);
    }

    // token lookup for L0 finishers (normal cached load, immutable input)
    int e = 25;
    if (!role && p < 256) {
      int tok = tokF[p * 32 + bF];
      e = (tok < 0) ? 25 : tok;
    }

    asm volatile("s_waitcnt vmcnt(0)" ::: "memory");
    __builtin_amdgcn_sched_barrier(0);

    f32x4 acc[2];
    acc[0] = f32x4{0.f, 0.f, 0.f, 0.f};
    acc[1] = f32x4{0.f, 0.f, 0.f, 0.f};
    if (role) {
#pragma unroll
      for (int kk = 0; kk < 16; ++kk) {
        int kabs = kq * 16 + kk;
        h16x8 a1 = __builtin_bit_cast(h16x8, A1r[kk]);
        h16x8 a2 = __builtin_bit_cast(h16x8, A2r[kk]);
#pragma unroll
        for (int nt = 0; nt < 2; ++nt) {
          h16x8 bi = *(const h16x8*)(wlds + ((size_t)((0 * 2 + nt) * 32 + kabs) * 64 + lane) * 8);
          h16x8 bh = *(const h16x8*)(wlds + ((size_t)((1 * 2 + nt) * 32 + kabs) * 64 + lane) * 8);
          acc[nt] = __builtin_amdgcn_mfma_f32_16x16x32_f16(a1, bi, acc[nt], 0, 0, 0);
          acc[nt] = __builtin_amdgcn_mfma_f32_16x16x32_f16(a2, bh, acc[nt], 0, 0, 0);
        }
      }
    } else {
#pragma unroll
      for (int kk = 0; kk < 16; ++kk) {
        int kabs = kq * 16 + kk;
        h16x8 a1 = __builtin_bit_cast(h16x8, A1r[kk]);
#pragma unroll
        for (int nt = 0; nt < 2; ++nt) {
          h16x8 b0 = *(const h16x8*)(wlds + ((size_t)(nt * 32 + kabs) * 64 + lane) * 8);
          acc[nt] = __builtin_amdgcn_mfma_f32_16x16x32_f16(a1, b0, acc[nt], 0, 0, 0);
        }
      }
    }

    // ---- partials: D row=(hi*4+q), col=nt*16+bl -> scr[kq][grow][col] ----
#pragma unroll
    for (int nt = 0; nt < 2; ++nt)
#pragma unroll
      for (int q = 0; q < 4; ++q)
        scr[(kq * 64 + rg * 16 + hi * 4 + q) * 36 + nt * 16 + bl] = acc[nt][q];
    __syncthreads();

    // ---- finish: all 512 threads, thread = (row=lane, j=wv) ----
    const bool act = role ? (p >= 1) : (p < 256);
    if (act) {
      const float* sb = scr + rowF * 36 + (jF << 2);
      f32x4 gv = *(const f32x4*)(sb) + *(const f32x4*)(sb + 64 * 36);
      float gi, gf, gg, go;
      int tcur;
      if (!role) {
        const f32x4 ib = *(const f32x4*)(ihbL + (e << 5) + (jF << 2));
        gi = gv[0] + ib[0]; gf = gv[1] + ib[1];
        gg = gv[2] + ib[2]; go = gv[3] + ib[3];
        tcur = p;
      } else {
        gi = gv[0] + bb[0]; gf = gv[1] + bb[1];
        gg = gv[2] + bb[2]; go = gv[3] + bb[3];
        tcur = p - 1;
      }
      if (tcur < lenF) {
        float iv = sigm(gi), fv = sigm(gf), gt = tanh_(gg), ov = sigm(go);
        cs = fv * cs + iv * gt;
        hv = ov * tanh_(cs);
      }
      if (!role) {
        stg_sc_h16(h1buf + (r ^ 1) * 65536 + rowF * 1024 + jglob, hv);
      } else {
        stg_sc_h16(h2buf + r * 65536 + rowF * 1024 + jglob, hv);
      }
    }

    if (p < 256) gbar(syncb, p);
  }
  // final h2 (t=255) lives in h2buf slot 0 (phase 256, r=0)
}

// ------------------------- head (lin+relu+out) -----------------------------

__global__ void __launch_bounds__(256) head_kernel(
    const h16* __restrict__ h2, const float* __restrict__ linW,
    const float* __restrict__ linb, const float* __restrict__ outW,
    const float* __restrict__ outb, float* __restrict__ out) {
  __shared__ h16 hl[2048];
  __shared__ float red[4];
  const int b = (int)blockIdx.x >> 2, lq = (int)blockIdx.x & 3;
  const int tid = (int)threadIdx.x;
  {
    int k0 = tid * 8;
    const h16* src = (k0 < 1024) ? (h2 + b * 1024 + k0)
                                 : (h2 + (b + 32) * 1024 + (k0 - 1024));
    *(h16x8*)(hl + k0) = *(const h16x8*)src;
  }
  __syncthreads();
  const int l = lq * 256 + tid;
  float acc = linb[l];
  const float* wr = linW + (size_t)l * 2048;
  for (int k = 0; k < 2048; k += 4) {
    float4 wv = *(const float4*)(wr + k);
    acc += wv.x * (float)hl[k] + wv.y * (float)hl[k + 1] +
           wv.z * (float)hl[k + 2] + wv.w * (float)hl[k + 3];
  }
  float v = fmaxf(acc, 0.f) * outW[l];
  for (int off = 32; off > 0; off >>= 1) v += __shfl_down(v, off);
  if ((tid & 63) == 0) red[tid >> 6] = v;
  __syncthreads();
  if (tid == 0) {
    float s = red[0] + red[1] + red[2] + red[3];
    if (lq == 0) s += outb[0];
    atomicAdd(out + b, s);
  }
}

// ------------------------- launcher ----------------------------------------

extern "C" void kernel_launch(void* const* d_in, const int* in_sizes, int n_in,
                              void* d_out, int out_size, void* d_ws,
                              size_t ws_size, hipStream_t stream) {
  (void)in_sizes; (void)n_in; (void)out_size; (void)ws_size;
  const float* emb  = (const float*)d_in[0];
  const float* wih0 = (const float*)d_in[1];
  const float* whh0 = (const float*)d_in[2];
  const float* bih0 = (const float*)d_in[3];
  const float* bhh0 = (const float*)d_in[4];
  const float* wih1 = (const float*)d_in[5];
  const float* whh1 = (const float*)d_in[6];
  const float* bih1 = (const float*)d_in[7];
  const float* bhh1 = (const float*)d_in[8];
  const float* linW = (const float*)d_in[9];
  const float* linb = (const float*)d_in[10];
  const float* outW = (const float*)d_in[11];
  const float* outb = (const float*)d_in[12];
  const int* tokL = (const int*)d_in[13];
  const int* tokR = (const int*)d_in[14];
  const int* lenL = (const int*)d_in[15];
  const int* lenR = (const int*)d_in[16];

  char* ws = (char*)d_ws;
  float* IHBp    = (float*)(ws + OFF_IHB);
  h16* H1p       = (h16*)(ws + OFF_H1);
  h16* H2p       = (h16*)(ws + OFF_H2);
  unsigned* SYp  = (unsigned*)(ws + OFF_SYNC);

  hipMemsetAsync(ws + ZERO_OFF, 0, ZERO_BYTES, stream);  // h state + barrier
  hipMemsetAsync(d_out, 0, 32 * sizeof(float), stream);

  prep_ihb<<<3328, 64, 0, stream>>>(emb, wih0, bih0, bhh0, IHBp);

  hipFuncSetAttribute((const void*)lstm_main,
                      hipFuncAttributeMaxDynamicSharedMemorySize, LDS_TOTAL);
  void* kargs[] = {(void*)&whh0, (void*)&wih1, (void*)&whh1, (void*)&IHBp,
                   (void*)&bih1, (void*)&bhh1, (void*)&H1p,  (void*)&H2p,
                   (void*)&SYp,  (void*)&tokL, (void*)&tokR, (void*)&lenL,
                   (void*)&lenR};
  hipLaunchCooperativeKernel((const void*)lstm_main, dim3(NWG), dim3(WGT),
                             kargs, (unsigned)LDS_TOTAL, stream);

  head_kernel<<<128, 256, 0, stream>>>(H2p, linW, linb, outW, outb,
                                       (float*)d_out);
}